// Round 4
// baseline (2208.090 us; speedup 1.0000x reference)
//
#include <hip/hip_runtime.h>
#include <stdint.h>

// TopKAbsolutes2D: B=64 rows, N=1,048,576 elems/row, K=256.
//
// R3 lesson: full 64M-element LDS-atomic histogram was ~400 µs (~6.7 cyc/elem).
// We only need the extreme tail -> sampled threshold + exact verify:
//   1. sample_kernel: per-row hist of first 16384 elems only; T_lo = bin whose
//      sample suffix >= 4K/64 (=> E[candidates] ~ 4K per row, distribution-free
//      concentration; any failure is caught and routed to the exact fallback).
//   2. main_kernel:   single stream of x: out=0 everywhere (256 MB write),
//      append (bits,idx) where absbits >= T_lo (~1K/row). 512 MB = floor.
//   3. select_kernel: verify K <= M <= cap (else flag row); exact rank among M
//      candidates (abs desc, idx asc == jax.lax.top_k tie-break); scatter top-K.
//   4. fallback_kernel: flag-gated exact path for ANY data: binary search the
//      K-th absbits via counting sweeps, then index binary search for the tie
//      boundary. ~no-op when not flagged (the normal case).
//
// Discipline: all ws offsets bounded by ws_size; only cand_count needs zeroing
// (256 B memset); row_tlo/flags overwritten every call; stale cand entries are
// never read past the current count.

#define NBINS   4096      // absbits >> 19
#define ROWS    64
#define FBLK    32        // main blocks per row
#define MAXCAP  16384u    // per-row candidate capacity ceiling
#define LDS_SEL 6144      // select stages candidates in LDS when M <= this (48 KiB)
#define SAMPLE_N 16384

__global__ void sample_kernel(const float* __restrict__ x, const int* __restrict__ topk,
                              unsigned* __restrict__ row_tlo, int n_per_row) {
    __shared__ unsigned h[NBINS];
    __shared__ unsigned csum[256];
    __shared__ unsigned ssum[16];
    int row = blockIdx.x;
    for (int i = threadIdx.x; i < NBINS; i += blockDim.x) h[i] = 0;
    __syncthreads();

    int sn = n_per_row < SAMPLE_N ? n_per_row : SAMPLE_N;
    const float4* xv = (const float4*)(x + (size_t)row * n_per_row);
    int nvec = sn / 4;
    for (int i = threadIdx.x; i < nvec; i += blockDim.x) {
        float4 v = xv[i];
        atomicAdd(&h[(__float_as_uint(v.x) & 0x7fffffffu) >> 19], 1u);
        atomicAdd(&h[(__float_as_uint(v.y) & 0x7fffffffu) >> 19], 1u);
        atomicAdd(&h[(__float_as_uint(v.z) & 0x7fffffffu) >> 19], 1u);
        atomicAdd(&h[(__float_as_uint(v.w) & 0x7fffffffu) >> 19], 1u);
    }
    __syncthreads();

    if (threadIdx.x < 256) {                       // 256 chunks x 16 bins
        unsigned s = 0;
        int b = threadIdx.x * 16;
        #pragma unroll
        for (int j = 0; j < 16; ++j) s += h[b + j];
        csum[threadIdx.x] = s;
    }
    __syncthreads();
    if (threadIdx.x < 16) {                        // 16 superchunks x 16 chunks
        unsigned s = 0;
        int c = threadIdx.x * 16;
        #pragma unroll
        for (int j = 0; j < 16; ++j) s += csum[c + j];
        ssum[threadIdx.x] = s;
    }
    __syncthreads();

    if (threadIdx.x == 0) {
        unsigned K = (unsigned)(*topk);
        unsigned ratio = (unsigned)(n_per_row / sn);            // 64
        unsigned target = (4u * K + ratio - 1u) / ratio;        // 16
        if (target < 1u) target = 1u;
        if (target > (unsigned)sn) target = (unsigned)sn;
        unsigned acc = 0;
        int sc, cc, b;
        for (sc = 15; sc >= 0; --sc) { if (acc + ssum[sc] >= target) break; acc += ssum[sc]; }
        if (sc < 0) sc = 0;
        for (cc = sc * 16 + 15; cc >= sc * 16; --cc) { if (acc + csum[cc] >= target) break; acc += csum[cc]; }
        if (cc < sc * 16) cc = sc * 16;
        for (b = cc * 16 + 15; b >= cc * 16; --b) { if (acc + h[b] >= target) break; acc += h[b]; }
        if (b < cc * 16) b = cc * 16;
        row_tlo[row] = (unsigned)b << 19;          // absbits-space threshold
    }
}

__global__ void main_kernel(const float* __restrict__ x, float* __restrict__ out,
                            const unsigned* __restrict__ row_tlo,
                            unsigned* __restrict__ cand_count,
                            uint2* __restrict__ cand, unsigned cap, int n_per_row) {
    int row = blockIdx.x / FBLK;
    int sub = blockIdx.x % FBLK;
    int chunk = n_per_row / FBLK;                  // 32768
    size_t base = (size_t)row * n_per_row + (size_t)sub * chunk;
    const float4* xv = (const float4*)(x + base);
    float4* ov = (float4*)(out + base);
    unsigned tlo = row_tlo[row];                   // wave-uniform
    unsigned idx_base = (unsigned)(sub * chunk);
    int nvec = chunk / 4;
    const float4 z = make_float4(0.f, 0.f, 0.f, 0.f);
    for (int i = threadIdx.x; i < nvec; i += blockDim.x) {
        float4 v = xv[i];
        ov[i] = z;
        unsigned bb[4] = {__float_as_uint(v.x), __float_as_uint(v.y),
                          __float_as_uint(v.z), __float_as_uint(v.w)};
        #pragma unroll
        for (int c = 0; c < 4; ++c) {
            if ((bb[c] & 0x7fffffffu) >= tlo) {
                unsigned pos = atomicAdd(&cand_count[row], 1u);
                if (pos < cap) cand[(size_t)row * cap + pos] =
                    make_uint2(bb[c], idx_base + (unsigned)i * 4u + (unsigned)c);
            }
        }
    }
}

__global__ void select_kernel(const unsigned* __restrict__ cand_count,
                              const uint2* __restrict__ cand, unsigned cap,
                              const int* __restrict__ topk,
                              unsigned* __restrict__ flags,
                              float* __restrict__ out, int n_per_row) {
    __shared__ uint2 lc[LDS_SEL];
    int row = blockIdx.x;
    unsigned K = (unsigned)(*topk);
    unsigned M = cand_count[row];
    unsigned flag = (M < K || M > cap) ? 1u : 0u;
    if (threadIdx.x == 0) flags[row] = flag;
    if (flag) return;
    const uint2* c = cand + (size_t)row * cap;
    if (M <= LDS_SEL) {
        for (unsigned i = threadIdx.x; i < M; i += blockDim.x) lc[i] = c[i];
        __syncthreads();
        for (unsigned i = threadIdx.x; i < M; i += blockDim.x) {
            uint2 ci = lc[i];
            unsigned ai = ci.x & 0x7fffffffu;
            unsigned rank = 0;
            for (unsigned j = 0; j < M; ++j) {
                uint2 cj = lc[j];
                unsigned aj = cj.x & 0x7fffffffu;
                rank += (unsigned)((aj > ai) || (aj == ai && cj.y < ci.y));
            }
            if (rank < K)
                out[(size_t)row * n_per_row + ci.y] = __uint_as_float(ci.x);
        }
    } else {
        for (unsigned i = threadIdx.x; i < M; i += blockDim.x) {
            uint2 ci = c[i];
            unsigned ai = ci.x & 0x7fffffffu;
            unsigned rank = 0;
            for (unsigned j = 0; j < M; ++j) {
                uint2 cj = c[j];
                unsigned aj = cj.x & 0x7fffffffu;
                rank += (unsigned)((aj > ai) || (aj == ai && cj.y < ci.y));
            }
            if (rank < K)
                out[(size_t)row * n_per_row + ci.y] = __uint_as_float(ci.x);
        }
    }
}

// Exact per-row top-K for any data; only runs when flags[row] != 0.
__device__ unsigned block_reduce_sum(unsigned v, unsigned* red) {
    red[threadIdx.x] = v;
    __syncthreads();
    for (int s = 128; s > 0; s >>= 1) {
        if ((int)threadIdx.x < s) red[threadIdx.x] += red[threadIdx.x + s];
        __syncthreads();
    }
    unsigned tot = red[0];
    __syncthreads();
    return tot;
}

__global__ void fallback_kernel(const float* __restrict__ x, float* __restrict__ out,
                                const unsigned* __restrict__ flags,
                                const int* __restrict__ topk, int n_per_row) {
    __shared__ unsigned red[256];
    int row = blockIdx.x;
    if (flags[row] == 0u) return;
    unsigned K = (unsigned)(*topk);
    if (K > (unsigned)n_per_row) K = (unsigned)n_per_row;
    const float* xr = x + (size_t)row * n_per_row;
    float* orow = out + (size_t)row * n_per_row;

    // binary search: largest m with count(absbits >= m) >= K
    unsigned lo = 0, hi = 0x7fffffffu;
    while (lo < hi) {
        unsigned mid = lo + (hi - lo + 1u) / 2u;
        unsigned c = 0;
        for (int i = threadIdx.x; i < n_per_row; i += blockDim.x)
            c += (unsigned)((__float_as_uint(xr[i]) & 0x7fffffffu) >= mid);
        unsigned tot = block_reduce_sum(c, red);
        if (tot >= K) lo = mid; else hi = mid - 1u;
    }
    unsigned Astar = lo;

    // count strictly greater
    unsigned cg = 0;
    for (int i = threadIdx.x; i < n_per_row; i += blockDim.x)
        cg += (unsigned)((__float_as_uint(xr[i]) & 0x7fffffffu) > Astar);
    unsigned c_gt = block_reduce_sum(cg, red);
    unsigned r_eq = K - c_gt;

    // scatter strictly-greater elements
    for (int i = threadIdx.x; i < n_per_row; i += blockDim.x) {
        unsigned bits = __float_as_uint(xr[i]);
        if ((bits & 0x7fffffffu) > Astar) orow[i] = __uint_as_float(bits);
    }

    // smallest I with count(absbits == Astar && idx < I) >= r_eq
    unsigned loI = 1, hiI = (unsigned)n_per_row;
    while (loI < hiI) {
        unsigned mid = (loI + hiI) / 2u;
        unsigned c = 0;
        for (unsigned i = threadIdx.x; i < (unsigned)n_per_row; i += blockDim.x)
            c += (unsigned)(((__float_as_uint(xr[i]) & 0x7fffffffu) == Astar) && i < mid);
        unsigned tot = block_reduce_sum(c, red);
        if (tot >= r_eq) hiI = mid; else loI = mid + 1u;
    }
    for (unsigned i = threadIdx.x; i < (unsigned)n_per_row; i += blockDim.x) {
        unsigned bits = __float_as_uint(xr[i]);
        if (((bits & 0x7fffffffu) == Astar) && i < hiI) orow[i] = __uint_as_float(bits);
    }
}

extern "C" void kernel_launch(void* const* d_in, const int* in_sizes, int n_in,
                              void* d_out, int out_size, void* d_ws, size_t ws_size,
                              hipStream_t stream) {
    const float* x  = (const float*)d_in[0];
    const int* topk = (const int*)d_in[1];
    float* out      = (float*)d_out;

    const int rows = ROWS;
    const int n_per_row = out_size / rows;         // 1,048,576

    // --- workspace layout (strictly within ws_size) ---
    uint8_t* ws = (uint8_t*)d_ws;
    unsigned* cand_count = (unsigned*)(ws + 0);    // 256 B, zeroed each call
    unsigned* row_tlo    = (unsigned*)(ws + 256);  // overwritten each call
    unsigned* flags      = (unsigned*)(ws + 512);  // overwritten each call
    size_t off = 1024;
    size_t avail = (ws_size > off) ? (ws_size - off) : 0;
    unsigned cap = (unsigned)(avail / ((size_t)rows * sizeof(uint2)));
    if (cap > MAXCAP) cap = MAXCAP;
    if (cap == 0) cap = 1;                         // degenerate: always fallback, still correct
    uint2* cand = (uint2*)(ws + off);

    hipMemsetAsync((void*)cand_count, 0, 256, stream);

    sample_kernel<<<rows, 1024, 0, stream>>>(x, topk, row_tlo, n_per_row);
    main_kernel<<<rows * FBLK, 256, 0, stream>>>(x, out, row_tlo, cand_count, cand,
                                                 cap, n_per_row);
    select_kernel<<<rows, 256, 0, stream>>>(cand_count, cand, cap, topk, flags,
                                            out, n_per_row);
    fallback_kernel<<<rows, 256, 0, stream>>>(x, out, flags, topk, n_per_row);
}

// Round 5
// 840.316 us; speedup vs baseline: 2.6277x; 2.6277x over previous
//
#include <hip/hip_runtime.h>
#include <stdint.h>

// TopKAbsolutes2D: B=64 rows, N=1,048,576 elems/row, K=256.
//
// R4 lesson: O(M^2) rank-by-broadcast-scan in select was a serial dependent
// LDS-read chain (8 VGPRs, no pipelining, 1.5% occupancy) -> 1402 us. Replaced
// with an LDS bitonic sort (P<=8192, ~66 parallel compare-exchange passes).
//
// Pipeline:
//   1. sample_kernel: per-row hist of first 16384 elems; T_lo = bin whose sample
//      suffix >= 4K/64 (=> E[candidates] ~ 1.2K/row). Also zeroes cand_count.
//   2. main_kernel:   single stream of x: out=0 everywhere (256 MB write),
//      append (bits,idx) where absbits >= T_lo. 512 MB traffic = structural floor.
//   3. select_kernel: if K <= M <= min(cap,8192): bitonic-sort candidates in LDS
//      (abs desc, idx asc == jax.lax.top_k tie-break), scatter first K. Else flag.
//   4. fallback_kernel: flag-gated exact path for ANY data (binary search K-th
//      absbits + index binary search for tie boundary). ~no-op normally.

#define NBINS    4096     // absbits >> 19
#define ROWS     64
#define FBLK     32       // main blocks per row
#define MAXCAP   16384u   // per-row candidate capacity ceiling
#define SORT_MAX 8192     // bitonic sort capacity (64 KiB LDS)
#define SAMPLE_N 16384

__global__ void sample_kernel(const float* __restrict__ x, const int* __restrict__ topk,
                              unsigned* __restrict__ row_tlo,
                              unsigned* __restrict__ cand_count, int n_per_row) {
    __shared__ unsigned h[NBINS];
    __shared__ unsigned csum[256];
    __shared__ unsigned ssum[16];
    int row = blockIdx.x;
    if (threadIdx.x == 0) cand_count[row] = 0;     // replaces host-side memset
    for (int i = threadIdx.x; i < NBINS; i += blockDim.x) h[i] = 0;
    __syncthreads();

    int sn = n_per_row < SAMPLE_N ? n_per_row : SAMPLE_N;
    const float4* xv = (const float4*)(x + (size_t)row * n_per_row);
    int nvec = sn / 4;
    for (int i = threadIdx.x; i < nvec; i += blockDim.x) {
        float4 v = xv[i];
        atomicAdd(&h[(__float_as_uint(v.x) & 0x7fffffffu) >> 19], 1u);
        atomicAdd(&h[(__float_as_uint(v.y) & 0x7fffffffu) >> 19], 1u);
        atomicAdd(&h[(__float_as_uint(v.z) & 0x7fffffffu) >> 19], 1u);
        atomicAdd(&h[(__float_as_uint(v.w) & 0x7fffffffu) >> 19], 1u);
    }
    __syncthreads();

    if (threadIdx.x < 256) {
        unsigned s = 0;
        int b = threadIdx.x * 16;
        #pragma unroll
        for (int j = 0; j < 16; ++j) s += h[b + j];
        csum[threadIdx.x] = s;
    }
    __syncthreads();
    if (threadIdx.x < 16) {
        unsigned s = 0;
        int c = threadIdx.x * 16;
        #pragma unroll
        for (int j = 0; j < 16; ++j) s += csum[c + j];
        ssum[threadIdx.x] = s;
    }
    __syncthreads();

    if (threadIdx.x == 0) {
        unsigned K = (unsigned)(*topk);
        unsigned ratio = (unsigned)(n_per_row / sn);            // 64
        unsigned target = (4u * K + ratio - 1u) / ratio;        // 16
        if (target < 1u) target = 1u;
        if (target > (unsigned)sn) target = (unsigned)sn;
        unsigned acc = 0;
        int sc, cc, b;
        for (sc = 15; sc >= 0; --sc) { if (acc + ssum[sc] >= target) break; acc += ssum[sc]; }
        if (sc < 0) sc = 0;
        for (cc = sc * 16 + 15; cc >= sc * 16; --cc) { if (acc + csum[cc] >= target) break; acc += csum[cc]; }
        if (cc < sc * 16) cc = sc * 16;
        for (b = cc * 16 + 15; b >= cc * 16; --b) { if (acc + h[b] >= target) break; acc += h[b]; }
        if (b < cc * 16) b = cc * 16;
        row_tlo[row] = (unsigned)b << 19;          // absbits-space threshold
    }
}

__global__ void main_kernel(const float* __restrict__ x, float* __restrict__ out,
                            const unsigned* __restrict__ row_tlo,
                            unsigned* __restrict__ cand_count,
                            uint2* __restrict__ cand, unsigned cap, int n_per_row) {
    int row = blockIdx.x / FBLK;
    int sub = blockIdx.x % FBLK;
    int chunk = n_per_row / FBLK;                  // 32768
    size_t base = (size_t)row * n_per_row + (size_t)sub * chunk;
    const float4* xv = (const float4*)(x + base);
    float4* ov = (float4*)(out + base);
    unsigned tlo = row_tlo[row];                   // wave-uniform
    unsigned idx_base = (unsigned)(sub * chunk);
    int nvec = chunk / 4;
    const float4 z = make_float4(0.f, 0.f, 0.f, 0.f);
    for (int i = threadIdx.x; i < nvec; i += blockDim.x) {
        float4 v = xv[i];
        ov[i] = z;
        unsigned bb[4] = {__float_as_uint(v.x), __float_as_uint(v.y),
                          __float_as_uint(v.z), __float_as_uint(v.w)};
        #pragma unroll
        for (int c = 0; c < 4; ++c) {
            if ((bb[c] & 0x7fffffffu) >= tlo) {
                unsigned pos = atomicAdd(&cand_count[row], 1u);
                if (pos < cap) cand[(size_t)row * cap + pos] =
                    make_uint2(bb[c], idx_base + (unsigned)i * 4u + (unsigned)c);
            }
        }
    }
}

// One 1024-thread block per row: bitonic sort candidates in LDS, scatter top-K.
__global__ void select_kernel(const unsigned* __restrict__ cand_count,
                              const uint2* __restrict__ cand, unsigned cap,
                              const int* __restrict__ topk,
                              unsigned* __restrict__ flags,
                              float* __restrict__ out, int n_per_row) {
    __shared__ uint2 lc[SORT_MAX];
    int row = blockIdx.x;
    unsigned K = (unsigned)(*topk);
    unsigned M = cand_count[row];
    unsigned flag = (M < K || M > cap || M > SORT_MAX) ? 1u : 0u;
    if (threadIdx.x == 0) flags[row] = flag;
    if (flag) return;

    unsigned P = 2;
    while (P < M) P <<= 1;                         // P <= SORT_MAX
    const uint2* c = cand + (size_t)row * cap;
    for (unsigned i = threadIdx.x; i < P; i += blockDim.x)
        lc[i] = (i < M) ? c[i] : make_uint2(0u, 0xFFFFFFFFu);   // pads sort last
    __syncthreads();

    // Bitonic sort, "ascending" under lt(a,b) = a is better (abs desc, idx asc).
    for (unsigned k = 2; k <= P; k <<= 1) {
        for (unsigned j = k >> 1; j > 0; j >>= 1) {
            for (unsigned t = threadIdx.x; t < (P >> 1); t += blockDim.x) {
                unsigned i = ((t & ~(j - 1u)) << 1) | (t & (j - 1u));
                unsigned p = i | j;
                uint2 a = lc[i], b = lc[p];
                unsigned aa = a.x & 0x7fffffffu, ab = b.x & 0x7fffffffu;
                bool b_before_a = (ab > aa) || (ab == aa && b.y < a.y);
                bool asc = ((i & k) == 0u);
                if (asc == b_before_a) { lc[i] = b; lc[p] = a; }
            }
            __syncthreads();
        }
    }
    for (unsigned t = threadIdx.x; t < K; t += blockDim.x) {
        uint2 e = lc[t];
        out[(size_t)row * n_per_row + e.y] = __uint_as_float(e.x);
    }
}

// Exact per-row top-K for any data; only runs when flags[row] != 0.
__device__ unsigned block_reduce_sum(unsigned v, unsigned* red) {
    red[threadIdx.x] = v;
    __syncthreads();
    for (int s = 128; s > 0; s >>= 1) {
        if ((int)threadIdx.x < s) red[threadIdx.x] += red[threadIdx.x + s];
        __syncthreads();
    }
    unsigned tot = red[0];
    __syncthreads();
    return tot;
}

__global__ void fallback_kernel(const float* __restrict__ x, float* __restrict__ out,
                                const unsigned* __restrict__ flags,
                                const int* __restrict__ topk, int n_per_row) {
    __shared__ unsigned red[256];
    int row = blockIdx.x;
    if (flags[row] == 0u) return;
    unsigned K = (unsigned)(*topk);
    if (K > (unsigned)n_per_row) K = (unsigned)n_per_row;
    const float* xr = x + (size_t)row * n_per_row;
    float* orow = out + (size_t)row * n_per_row;

    unsigned lo = 0, hi = 0x7fffffffu;             // largest m: count(abs>=m) >= K
    while (lo < hi) {
        unsigned mid = lo + (hi - lo + 1u) / 2u;
        unsigned c = 0;
        for (int i = threadIdx.x; i < n_per_row; i += blockDim.x)
            c += (unsigned)((__float_as_uint(xr[i]) & 0x7fffffffu) >= mid);
        unsigned tot = block_reduce_sum(c, red);
        if (tot >= K) lo = mid; else hi = mid - 1u;
    }
    unsigned Astar = lo;

    unsigned cg = 0;
    for (int i = threadIdx.x; i < n_per_row; i += blockDim.x)
        cg += (unsigned)((__float_as_uint(xr[i]) & 0x7fffffffu) > Astar);
    unsigned c_gt = block_reduce_sum(cg, red);
    unsigned r_eq = K - c_gt;

    for (int i = threadIdx.x; i < n_per_row; i += blockDim.x) {
        unsigned bits = __float_as_uint(xr[i]);
        if ((bits & 0x7fffffffu) > Astar) orow[i] = __uint_as_float(bits);
    }

    unsigned loI = 1, hiI = (unsigned)n_per_row;   // tie boundary by index
    while (loI < hiI) {
        unsigned mid = (loI + hiI) / 2u;
        unsigned c = 0;
        for (unsigned i = threadIdx.x; i < (unsigned)n_per_row; i += blockDim.x)
            c += (unsigned)(((__float_as_uint(xr[i]) & 0x7fffffffu) == Astar) && i < mid);
        unsigned tot = block_reduce_sum(c, red);
        if (tot >= r_eq) hiI = mid; else loI = mid + 1u;
    }
    for (unsigned i = threadIdx.x; i < (unsigned)n_per_row; i += blockDim.x) {
        unsigned bits = __float_as_uint(xr[i]);
        if (((bits & 0x7fffffffu) == Astar) && i < hiI) orow[i] = __uint_as_float(bits);
    }
}

extern "C" void kernel_launch(void* const* d_in, const int* in_sizes, int n_in,
                              void* d_out, int out_size, void* d_ws, size_t ws_size,
                              hipStream_t stream) {
    const float* x  = (const float*)d_in[0];
    const int* topk = (const int*)d_in[1];
    float* out      = (float*)d_out;

    const int rows = ROWS;
    const int n_per_row = out_size / rows;         // 1,048,576

    // --- workspace layout (strictly within ws_size) ---
    uint8_t* ws = (uint8_t*)d_ws;
    unsigned* cand_count = (unsigned*)(ws + 0);    // zeroed by sample_kernel
    unsigned* row_tlo    = (unsigned*)(ws + 256);  // overwritten each call
    unsigned* flags      = (unsigned*)(ws + 512);  // overwritten each call
    size_t off = 1024;
    size_t avail = (ws_size > off) ? (ws_size - off) : 0;
    unsigned cap = (unsigned)(avail / ((size_t)rows * sizeof(uint2)));
    if (cap > MAXCAP) cap = MAXCAP;
    if (cap == 0) cap = 1;                         // degenerate: always fallback
    uint2* cand = (uint2*)(ws + off);

    sample_kernel<<<rows, 1024, 0, stream>>>(x, topk, row_tlo, cand_count, n_per_row);
    main_kernel<<<rows * FBLK, 256, 0, stream>>>(x, out, row_tlo, cand_count, cand,
                                                 cap, n_per_row);
    select_kernel<<<rows, 1024, 0, stream>>>(cand_count, cand, cap, topk, flags,
                                             out, n_per_row);
    fallback_kernel<<<rows, 256, 0, stream>>>(x, out, flags, topk, n_per_row);
}